// Round 12
// baseline (435.412 us; speedup 1.0000x reference)
//
#include <hip/hip_runtime.h>
#include <hip/hip_bf16.h>

// GCN: 2x GCNConv(+self-loops, sym-norm) + ReLU, then Linear(64->1).
// N=100000 nodes, E=1600000 edges, IN=128, HID=64, OUT=1.
//
//  - R11 post-mortem: agg at its floor (~46.7us: compulsory 85MB FETCH
//    across 8 XCD L2s + VALU 53%); FROZEN as control.
//  - R12: (a) gemm was LDS-read-bound (32B LDS / 16 FMA): now 128x64
//    tile, 8x4 per-thread blocking -> 48B / 32 FMA, 782 blocks.
//    (b) build_csr had 98 blocks on 256 CUs: now 256-node buckets
//    (NC=391 blocks x 256 thr, 4K edges each), pairs = (src<<8)|loc.
//  - Ts/h1 stored bf16 (packed bf16x2); fp32 accumulate everywhere.
//  - norm factored into GEMM epilogue: out[d]=dq_d*(Ts[d]+sum Ts[s]).

#define IN_DIM 128
#define HID 64
#define B1 256        // level-1 blocks (chunks)
#define MAXNC 512     // max coarse buckets (N <= 131072)

typedef unsigned int uint;

__device__ inline uint pack_bf16x2(float a, float b) {
    uint ua = __builtin_bit_cast(uint, a);
    uint ub = __builtin_bit_cast(uint, b);
    ua += 0x7fffu + ((ua >> 16) & 1u);   // RNE
    ub += 0x7fffu + ((ub >> 16) & 1u);
    return (ua >> 16) | (ub & 0xffff0000u);
}
__device__ inline float bf_lo(uint g) { return __builtin_bit_cast(float, g << 16); }
__device__ inline float bf_hi(uint g) { return __builtin_bit_cast(float, g & 0xffff0000u); }

// ---------------- level-1 histogram: coarse buckets (dst>>8) per chunk ----------------
__global__ __launch_bounds__(512) void hist1(const int* __restrict__ dst,
                                             int* __restrict__ ghist,
                                             int E, int NC, int chunk) {
    __shared__ int h[MAXNC];
    int t = threadIdx.x, blk = blockIdx.x;
    if (t < NC) h[t] = 0;
    __syncthreads();
    int s = blk * chunk, e = min(E, s + chunk);
    for (int i = s + t; i < e; i += 512) atomicAdd(&h[dst[i] >> 8], 1);
    __syncthreads();
    if (t < NC) ghist[(size_t)t * B1 + blk] = h[t];
}

// ---------------- exclusive scan of ghist (NC*B1 elems, in place) ----------------
__global__ __launch_bounds__(1024) void scan_mat(int* __restrict__ a, int M,
                                                 int* __restrict__ row_off, int N) {
    __shared__ int ws[16], wsoff[16], total_s;
    int t = threadIdx.x;
    int seg = (M + 1023) >> 10;
    int s = t * seg, e = min(M, s + seg);
    int sum = 0;
    for (int i = s; i < e; ++i) sum += a[i];
    int incl = sum;
#pragma unroll
    for (int o = 1; o < 64; o <<= 1) {
        int u = __shfl_up(incl, o, 64);
        if ((t & 63) >= o) incl += u;
    }
    if ((t & 63) == 63) ws[t >> 6] = incl;
    __syncthreads();
    if (t == 0) {
        int run = 0;
#pragma unroll
        for (int i = 0; i < 16; ++i) { wsoff[i] = run; run += ws[i]; }
        total_s = run;
    }
    __syncthreads();
    int run = wsoff[t >> 6] + incl - sum;  // exclusive prefix at segment start
    for (int i = s; i < e; ++i) { int tmp = a[i]; a[i] = run; run += tmp; }
    if (t == 0) row_off[N] = total_s;  // == E
}

// ---------------- level-1 scatter: packed 4B pairs, sequential runs ----------------
__global__ __launch_bounds__(512) void scatter1(const int* __restrict__ src,
                                                const int* __restrict__ dst,
                                                const int* __restrict__ goff,
                                                uint* __restrict__ pairs,
                                                int E, int NC, int chunk) {
    __shared__ int cur[MAXNC];
    int t = threadIdx.x, blk = blockIdx.x;
    if (t < NC) cur[t] = goff[(size_t)t * B1 + blk];
    __syncthreads();
    int s = blk * chunk, e = min(E, s + chunk);
    for (int i = s + t; i < e; i += 512) {
        int d = dst[i];
        int p = atomicAdd(&cur[d >> 8], 1);   // LDS cursor holds global pos
        pairs[p] = ((uint)src[i] << 8) | (uint)(d & 255);
    }
}

// ---------------- level-2: per-bucket CSR build (exact, 256-node buckets) ----------------
__global__ __launch_bounds__(256) void build_csr(const uint* __restrict__ pairs,
                                                 const int* __restrict__ goff,
                                                 int* __restrict__ row_off,
                                                 float* __restrict__ disqrt,
                                                 int* __restrict__ col,
                                                 int E, int NC, int N) {
    __shared__ int h[256], cur[256];
    __shared__ int ws[4], wsoff[4];
    int b = blockIdx.x, t = threadIdx.x;
    int base = goff[(size_t)b * B1];
    int next = (b + 1 < NC) ? goff[(size_t)(b + 1) * B1] : E;
    h[t] = 0;
    __syncthreads();
    for (int i = base + t; i < next; i += 256)
        atomicAdd(&h[pairs[i] & 255u], 1);
    __syncthreads();
    int deg = h[t];
    int incl = deg;
#pragma unroll
    for (int o = 1; o < 64; o <<= 1) {
        int u = __shfl_up(incl, o, 64);
        if ((t & 63) >= o) incl += u;
    }
    if ((t & 63) == 63) ws[t >> 6] = incl;
    __syncthreads();
    if (t == 0) {
        int run = 0;
#pragma unroll
        for (int i = 0; i < 4; ++i) { wsoff[i] = run; run += ws[i]; }
    }
    __syncthreads();
    int excl = wsoff[t >> 6] + incl - deg;
    cur[t] = base + excl;
    int node = (b << 8) + t;
    if (node < N) {
        row_off[node] = base + excl;
        disqrt[node]  = rsqrtf((float)(deg + 1));  // +1 self-loop
    }
    __syncthreads();
    for (int i = base + t; i < next; i += 256) {
        uint p = pairs[i];
        int pos = atomicAdd(&cur[p & 255u], 1);   // LDS atomic, global pos
        col[pos] = (int)(p >> 8);                 // 16KB window, single XCD
    }
}

// ---------------- tiled GEMM (fp32 X, K=128): 128x64 tile, 8x4/thread ----------------
template <int K>
__global__ __launch_bounds__(256) void gemm_tile(const float* __restrict__ X,
                                                 const float* __restrict__ W,
                                                 const float* __restrict__ disqrt,
                                                 uint* __restrict__ Tsb, int n) {
    __shared__ float xs[32][132];  // [k][m], 128 rows +4 pad (16B-aligned rows)
    __shared__ float ws[32][64];   // [k][c]
    const int tid = threadIdx.x;
    const int ng  = tid & 15;      // cols 4*ng..+3
    const int mg  = tid >> 4;      // rows 8*mg..+7
    const int m0  = blockIdx.x * 128;
    const float4 z4 = make_float4(0.f, 0.f, 0.f, 0.f);
    // staging geometry: X: 4 float4/thread (128 rows x 8 f4-slots);
    //                   W: 2 float4/thread (32 k x 16 f4-slots)
    int xr[4], xk[4];
#pragma unroll
    for (int i = 0; i < 4; ++i) { int f = tid + i * 256; xr[i] = f >> 3; xk[i] = f & 7; }
    const int wk0 = tid >> 4, wc0 = tid & 15;

    float4 gx[4], gw[2];
#pragma unroll
    for (int i = 0; i < 4; ++i) {
        int row = m0 + xr[i];
        gx[i] = (row < n) ? *(const float4*)(X + (size_t)row * K + 4 * xk[i]) : z4;
    }
    gw[0] = *(const float4*)(W + (size_t)wk0 * 64 + 4 * wc0);
    gw[1] = *(const float4*)(W + (size_t)(wk0 + 16) * 64 + 4 * wc0);

    float acc[8][4] = {};
    for (int kc = 0;;) {
#pragma unroll
        for (int i = 0; i < 4; ++i) {
            xs[4 * xk[i] + 0][xr[i]] = gx[i].x;
            xs[4 * xk[i] + 1][xr[i]] = gx[i].y;
            xs[4 * xk[i] + 2][xr[i]] = gx[i].z;
            xs[4 * xk[i] + 3][xr[i]] = gx[i].w;
        }
        *(float4*)&ws[wk0][4 * wc0]      = gw[0];
        *(float4*)&ws[wk0 + 16][4 * wc0] = gw[1];
        __syncthreads();
        kc += 32;
        const bool more = kc < K;
        if (more) {
#pragma unroll
            for (int i = 0; i < 4; ++i) {
                int row = m0 + xr[i];
                gx[i] = (row < n) ? *(const float4*)(X + (size_t)row * K + kc + 4 * xk[i]) : z4;
            }
            gw[0] = *(const float4*)(W + (size_t)(kc + wk0) * 64 + 4 * wc0);
            gw[1] = *(const float4*)(W + (size_t)(kc + wk0 + 16) * 64 + 4 * wc0);
        }
#pragma unroll 4
        for (int k = 0; k < 32; ++k) {
            float4 a0 = *(const float4*)&xs[k][8 * mg];
            float4 a1 = *(const float4*)&xs[k][8 * mg + 4];
            float4 b  = *(const float4*)&ws[k][4 * ng];
            const float* ap0 = (const float*)&a0;
            const float* ap1 = (const float*)&a1;
            const float* bp  = (const float*)&b;
#pragma unroll
            for (int mi = 0; mi < 4; ++mi)
#pragma unroll
                for (int ni = 0; ni < 4; ++ni) {
                    acc[mi][ni]     += ap0[mi] * bp[ni];
                    acc[mi + 4][ni] += ap1[mi] * bp[ni];
                }
        }
        if (!more) break;
        __syncthreads();
    }
#pragma unroll
    for (int mi = 0; mi < 8; ++mi) {
        int row = m0 + 8 * mg + mi;
        if (row < n) {
            float s = disqrt[row];
            uint2 pk;
            pk.x = pack_bf16x2(acc[mi][0] * s, acc[mi][1] * s);
            pk.y = pack_bf16x2(acc[mi][2] * s, acc[mi][3] * s);
            *(uint2*)(Tsb + (size_t)row * 32 + 2 * ng) = pk;
        }
    }
}

// ---------------- tiled GEMM (bf16 X, K=64): 128x64 tile, 8x4/thread ----------------
__global__ __launch_bounds__(256) void gemm_tile_b(const uint* __restrict__ Xb,
                                                   const float* __restrict__ W,
                                                   const float* __restrict__ disqrt,
                                                   uint* __restrict__ Tsb, int n) {
    const int K = 64;
    __shared__ float xs[32][132];
    __shared__ float ws[32][64];
    const int tid = threadIdx.x;
    const int ng  = tid & 15;
    const int mg  = tid >> 4;
    const int m0  = blockIdx.x * 128;
    const uint2 z2 = make_uint2(0u, 0u);
    // X chunk: 128 rows x 16 uints (32 bf16) = 2048 uints = 1024 uint2 -> 4/thread
    int xr[4], xk[4];
#pragma unroll
    for (int i = 0; i < 4; ++i) { int f = tid + i * 256; xr[i] = f >> 3; xk[i] = f & 7; }
    const int wk0 = tid >> 4, wc0 = tid & 15;

    uint2 gx[4];
    float4 gw[2];
#pragma unroll
    for (int i = 0; i < 4; ++i) {
        int row = m0 + xr[i];
        gx[i] = (row < n) ? *(const uint2*)(Xb + (size_t)row * 32 + 2 * xk[i]) : z2;
    }
    gw[0] = *(const float4*)(W + (size_t)wk0 * 64 + 4 * wc0);
    gw[1] = *(const float4*)(W + (size_t)(wk0 + 16) * 64 + 4 * wc0);

    float acc[8][4] = {};
    for (int kc = 0;;) {
#pragma unroll
        for (int i = 0; i < 4; ++i) {
            xs[4 * xk[i] + 0][xr[i]] = bf_lo(gx[i].x);
            xs[4 * xk[i] + 1][xr[i]] = bf_hi(gx[i].x);
            xs[4 * xk[i] + 2][xr[i]] = bf_lo(gx[i].y);
            xs[4 * xk[i] + 3][xr[i]] = bf_hi(gx[i].y);
        }
        *(float4*)&ws[wk0][4 * wc0]      = gw[0];
        *(float4*)&ws[wk0 + 16][4 * wc0] = gw[1];
        __syncthreads();
        kc += 32;
        const bool more = kc < K;
        if (more) {
#pragma unroll
            for (int i = 0; i < 4; ++i) {
                int row = m0 + xr[i];
                gx[i] = (row < n) ? *(const uint2*)(Xb + (size_t)row * 32 + 16 + 2 * xk[i]) : z2;
            }
            gw[0] = *(const float4*)(W + (size_t)(kc + wk0) * 64 + 4 * wc0);
            gw[1] = *(const float4*)(W + (size_t)(kc + wk0 + 16) * 64 + 4 * wc0);
        }
#pragma unroll 4
        for (int k = 0; k < 32; ++k) {
            float4 a0 = *(const float4*)&xs[k][8 * mg];
            float4 a1 = *(const float4*)&xs[k][8 * mg + 4];
            float4 b  = *(const float4*)&ws[k][4 * ng];
            const float* ap0 = (const float*)&a0;
            const float* ap1 = (const float*)&a1;
            const float* bp  = (const float*)&b;
#pragma unroll
            for (int mi = 0; mi < 4; ++mi)
#pragma unroll
                for (int ni = 0; ni < 4; ++ni) {
                    acc[mi][ni]     += ap0[mi] * bp[ni];
                    acc[mi + 4][ni] += ap1[mi] * bp[ni];
                }
        }
        if (!more) break;
        __syncthreads();
    }
#pragma unroll
    for (int mi = 0; mi < 8; ++mi) {
        int row = m0 + 8 * mg + mi;
        if (row < n) {
            float s = disqrt[row];
            uint2 pk;
            pk.x = pack_bf16x2(acc[mi][0] * s, acc[mi][1] * s);
            pk.y = pack_bf16x2(acc[mi][2] * s, acc[mi][3] * s);
            *(uint2*)(Tsb + (size_t)row * 32 + 2 * ng) = pk;
        }
    }
}

// ---------------- aggregation: wave per node, eighth-wave per edge (FROZEN) ----------------
template <bool FUSE_FC>
__global__ __launch_bounds__(256) void agg_kernel(const uint* __restrict__ Tsb,
                                                  const int* __restrict__ row_off,
                                                  const int* __restrict__ col,
                                                  const float* __restrict__ disqrt,
                                                  const float* __restrict__ bias,
                                                  const float* __restrict__ wfc,
                                                  const float* __restrict__ bfc,
                                                  uint* __restrict__ outb,
                                                  float* __restrict__ outf, int n) {
    int node = blockIdx.x * 4 + (threadIdx.x >> 6);
    if (node >= n) return;
    int lane = threadIdx.x & 63;
    int o = lane >> 3;      // octant id: edge slot within group of 8
    int p = lane & 7;       // uint4 index (features 8p..8p+7)
    float acc[8] = {};
    if (o == 0) {   // self-loop, octant 0 only
        uint4 g = *(const uint4*)(Tsb + (size_t)node * 32 + 4 * p);
        acc[0] = bf_lo(g.x); acc[1] = bf_hi(g.x);
        acc[2] = bf_lo(g.y); acc[3] = bf_hi(g.y);
        acc[4] = bf_lo(g.z); acc[5] = bf_hi(g.z);
        acc[6] = bf_lo(g.w); acc[7] = bf_hi(g.w);
    }
    int beg = __builtin_amdgcn_readfirstlane(row_off[node]);
    int end = __builtin_amdgcn_readfirstlane(row_off[node + 1]);
    for (int batch = beg; batch < end; batch += 64) {
        int bn = min(64, end - batch);
        int cv = 0;
        if (batch + lane < end) cv = col[batch + lane];  // ONE coalesced load
        int j = 0;
        for (; j + 16 <= bn; j += 16) {
            int s0 = __shfl(cv, j + o, 64);
            int s1 = __shfl(cv, j + 8 + o, 64);
            uint4 g0 = *(const uint4*)(Tsb + (size_t)s0 * 32 + 4 * p);
            uint4 g1 = *(const uint4*)(Tsb + (size_t)s1 * 32 + 4 * p);
            acc[0] += bf_lo(g0.x); acc[1] += bf_hi(g0.x);
            acc[2] += bf_lo(g0.y); acc[3] += bf_hi(g0.y);
            acc[4] += bf_lo(g0.z); acc[5] += bf_hi(g0.z);
            acc[6] += bf_lo(g0.w); acc[7] += bf_hi(g0.w);
            acc[0] += bf_lo(g1.x); acc[1] += bf_hi(g1.x);
            acc[2] += bf_lo(g1.y); acc[3] += bf_hi(g1.y);
            acc[4] += bf_lo(g1.z); acc[5] += bf_hi(g1.z);
            acc[6] += bf_lo(g1.w); acc[7] += bf_hi(g1.w);
        }
        for (; j < bn; j += 8) {
            int idx = j + o;
            int s = __shfl(cv, idx & 63, 64);
            uint4 g = *(const uint4*)(Tsb + (size_t)s * 32 + 4 * p);
            if (idx < bn) {
                acc[0] += bf_lo(g.x); acc[1] += bf_hi(g.x);
                acc[2] += bf_lo(g.y); acc[3] += bf_hi(g.y);
                acc[4] += bf_lo(g.z); acc[5] += bf_hi(g.z);
                acc[6] += bf_lo(g.w); acc[7] += bf_hi(g.w);
            }
        }
    }
#pragma unroll
    for (int k = 0; k < 8; ++k) {
        acc[k] += __shfl_xor(acc[k], 8, 64);
        acc[k] += __shfl_xor(acc[k], 16, 64);
        acc[k] += __shfl_xor(acc[k], 32, 64);
    }
    float dq = disqrt[node];
    float4 bv0 = *(const float4*)(bias + 8 * p);
    float4 bv1 = *(const float4*)(bias + 8 * p + 4);
    float r[8];
    r[0] = fmaxf(acc[0] * dq + bv0.x, 0.f);
    r[1] = fmaxf(acc[1] * dq + bv0.y, 0.f);
    r[2] = fmaxf(acc[2] * dq + bv0.z, 0.f);
    r[3] = fmaxf(acc[3] * dq + bv0.w, 0.f);
    r[4] = fmaxf(acc[4] * dq + bv1.x, 0.f);
    r[5] = fmaxf(acc[5] * dq + bv1.y, 0.f);
    r[6] = fmaxf(acc[6] * dq + bv1.z, 0.f);
    r[7] = fmaxf(acc[7] * dq + bv1.w, 0.f);
    if (!FUSE_FC) {
        if (o == 0) {   // pack to bf16 for gemm_tile_b
            uint4 pk;
            pk.x = pack_bf16x2(r[0], r[1]);
            pk.y = pack_bf16x2(r[2], r[3]);
            pk.z = pack_bf16x2(r[4], r[5]);
            pk.w = pack_bf16x2(r[6], r[7]);
            *(uint4*)(outb + (size_t)node * 32 + 4 * p) = pk;
        }
    } else {
        float4 wv0 = *(const float4*)(wfc + 8 * p);
        float4 wv1 = *(const float4*)(wfc + 8 * p + 4);
        float v = r[0] * wv0.x + r[1] * wv0.y + r[2] * wv0.z + r[3] * wv0.w +
                  r[4] * wv1.x + r[5] * wv1.y + r[6] * wv1.z + r[7] * wv1.w;
        v += __shfl_down(v, 4, 64);
        v += __shfl_down(v, 2, 64);
        v += __shfl_down(v, 1, 64);
        if (lane == 0) outf[node] = v + bfc[0];
    }
}

extern "C" void kernel_launch(void* const* d_in, const int* in_sizes, int n_in,
                              void* d_out, int out_size, void* d_ws, size_t ws_size,
                              hipStream_t stream) {
    const float* x   = (const float*)d_in[0];
    const int*   ei  = (const int*)d_in[1];
    const float* W1  = (const float*)d_in[2];
    const float* b1  = (const float*)d_in[3];
    const float* W2  = (const float*)d_in[4];
    const float* b2  = (const float*)d_in[5];
    const float* Wfc = (const float*)d_in[6];
    const float* bfc = (const float*)d_in[7];
    float* out = (float*)d_out;

    const int N = in_sizes[0] / IN_DIM;
    const int E = in_sizes[1] / 2;
    const int* src = ei;
    const int* dst = ei + E;
    const int NC    = (N + 255) >> 8;        // 256-node buckets
    const int chunk = (E + B1 - 1) / B1;     // edges per level-1 block

    // ---- workspace carve-up (256B aligned) ----
    char* w = (char*)d_ws;
    auto alloc = [&](size_t bytes) {
        void* p = (void*)w;
        w += (bytes + 255) & ~(size_t)255;
        return p;
    };
    int*   row_off = (int*)alloc((size_t)(N + 1) * 4);
    float* disqrt  = (float*)alloc((size_t)N * 4);
    int*   goff    = (int*)alloc((size_t)NC * B1 * 4);
    int*   col     = (int*)alloc((size_t)E * 4);
    // scratch region reused: packed pairs (E*4) first, then Ts bf16 (N*128B)
    size_t scrA = (size_t)E * 4, scrB = (size_t)N * HID * 2;
    void*  scr  = alloc(scrA > scrB ? scrA : scrB);
    uint*  h1b  = (uint*)alloc((size_t)N * HID * 2);   // h1 in packed bf16
    uint*  pairs = (uint*)scr;
    uint*  Tsb   = (uint*)scr;

    // ---- build CSR (exact two-level counting sort, packed pairs) ----
    hist1<<<B1, 512, 0, stream>>>(dst, goff, E, NC, chunk);
    scan_mat<<<1, 1024, 0, stream>>>(goff, NC * B1, row_off, N);
    scatter1<<<B1, 512, 0, stream>>>(src, dst, goff, pairs, E, NC, chunk);
    build_csr<<<NC, 256, 0, stream>>>(pairs, goff, row_off, disqrt, col, E, NC, N);

    // ---- layer 1 ----
    gemm_tile<IN_DIM><<<(N + 127) / 128, 256, 0, stream>>>(x, W1, disqrt, Tsb, N);
    agg_kernel<false><<<(N + 3) / 4, 256, 0, stream>>>(Tsb, row_off, col, disqrt,
                                                       b1, nullptr, nullptr,
                                                       h1b, nullptr, N);

    // ---- layer 2 + fused fc ----
    gemm_tile_b<<<(N + 127) / 128, 256, 0, stream>>>(h1b, W2, disqrt, Tsb, N);
    agg_kernel<true><<<(N + 3) / 4, 256, 0, stream>>>(Tsb, row_off, col, disqrt,
                                                      b2, Wfc, bfc,
                                                      nullptr, out, N);
}

// Round 13
// 280.629 us; speedup vs baseline: 1.5516x; 1.5516x over previous
//
#include <hip/hip_runtime.h>
#include <hip/hip_bf16.h>

// GCN: 2x GCNConv(+self-loops, sym-norm) + ReLU, then Linear(64->1).
// N=100000 nodes, E=1600000 edges, IN=128, HID=64, OUT=1.
//
//  - R12 post-mortem: 256-node buckets made M=NC*B1=100K and the
//    single-block scan_mat went serial (163us @ 0.16% occ) — the R1
//    scan mistake recurring. Replaced with 3-pass multi-block scan
//    (reduce -> scan block sums -> local scan + offset).
//  - agg FROZEN (floor ~46.7us: compulsory 85MB FETCH over 8 XCD L2s).
//  - gemm: 128x64 tile, 8x4/thread (LDS-read traffic halved per FMA).
//  - build_csr: 256-node buckets, 391 blocks.
//  - Ts/h1 stored bf16 (packed bf16x2); fp32 accumulate everywhere.
//  - norm factored into GEMM epilogue: out[d]=dq_d*(Ts[d]+sum Ts[s]).

#define IN_DIM 128
#define HID 64
#define B1 256        // level-1 blocks (chunks)
#define MAXNC 512     // max coarse buckets (N <= 131072)

typedef unsigned int uint;

__device__ inline uint pack_bf16x2(float a, float b) {
    uint ua = __builtin_bit_cast(uint, a);
    uint ub = __builtin_bit_cast(uint, b);
    ua += 0x7fffu + ((ua >> 16) & 1u);   // RNE
    ub += 0x7fffu + ((ub >> 16) & 1u);
    return (ua >> 16) | (ub & 0xffff0000u);
}
__device__ inline float bf_lo(uint g) { return __builtin_bit_cast(float, g << 16); }
__device__ inline float bf_hi(uint g) { return __builtin_bit_cast(float, g & 0xffff0000u); }

// ---------------- level-1 histogram: coarse buckets (dst>>8) per chunk ----------------
__global__ __launch_bounds__(512) void hist1(const int* __restrict__ dst,
                                             int* __restrict__ ghist,
                                             int E, int NC, int chunk) {
    __shared__ int h[MAXNC];
    int t = threadIdx.x, blk = blockIdx.x;
    if (t < NC) h[t] = 0;
    __syncthreads();
    int s = blk * chunk, e = min(E, s + chunk);
    for (int i = s + t; i < e; i += 512) atomicAdd(&h[dst[i] >> 8], 1);
    __syncthreads();
    if (t < NC) ghist[(size_t)t * B1 + blk] = h[t];
}

// ---------------- multi-block exclusive scan over ghist (M = NC*B1 elems) ----------------
// pass1: per-256-block reduce
__global__ __launch_bounds__(256) void scan_p1(const int* __restrict__ a,
                                               int* __restrict__ bsum, int M) {
    int i = blockIdx.x * 256 + threadIdx.x;
    int v = (i < M) ? a[i] : 0;
#pragma unroll
    for (int o = 32; o; o >>= 1) v += __shfl_down(v, o, 64);
    __shared__ int ws[4];
    int lane = threadIdx.x & 63, wid = threadIdx.x >> 6;
    if (lane == 0) ws[wid] = v;
    __syncthreads();
    if (threadIdx.x == 0) bsum[blockIdx.x] = ws[0] + ws[1] + ws[2] + ws[3];
}

// pass2: single block scans block sums (nb <= 512); writes row_off[N] = total (== E)
__global__ __launch_bounds__(512) void scan_p2(const int* __restrict__ bsum,
                                               int* __restrict__ boff,
                                               int* __restrict__ row_off,
                                               int nb, int N) {
    __shared__ int s[512];
    int t = threadIdx.x;
    int v = (t < nb) ? bsum[t] : 0;
    s[t] = v;
    __syncthreads();
#pragma unroll
    for (int o = 1; o < 512; o <<= 1) {
        int add = (t >= o) ? s[t - o] : 0;
        __syncthreads();
        s[t] += add;
        __syncthreads();
    }
    if (t < nb) boff[t] = s[t] - v;  // exclusive
    if (t == nb - 1) row_off[N] = s[t];
}

// pass3: block-local exclusive scan + block offset, in place
__global__ __launch_bounds__(256) void scan_p3(int* __restrict__ a,
                                               const int* __restrict__ boff, int M) {
    __shared__ int s[256];
    int i = blockIdx.x * 256 + threadIdx.x;
    int t = threadIdx.x;
    int d = (i < M) ? a[i] : 0;
    s[t] = d;
    __syncthreads();
#pragma unroll
    for (int o = 1; o < 256; o <<= 1) {
        int add = (t >= o) ? s[t - o] : 0;
        __syncthreads();
        s[t] += add;
        __syncthreads();
    }
    if (i < M) a[i] = s[t] - d + boff[blockIdx.x];
}

// ---------------- level-1 scatter: packed 4B pairs, sequential runs ----------------
__global__ __launch_bounds__(512) void scatter1(const int* __restrict__ src,
                                                const int* __restrict__ dst,
                                                const int* __restrict__ goff,
                                                uint* __restrict__ pairs,
                                                int E, int NC, int chunk) {
    __shared__ int cur[MAXNC];
    int t = threadIdx.x, blk = blockIdx.x;
    if (t < NC) cur[t] = goff[(size_t)t * B1 + blk];
    __syncthreads();
    int s = blk * chunk, e = min(E, s + chunk);
    for (int i = s + t; i < e; i += 512) {
        int d = dst[i];
        int p = atomicAdd(&cur[d >> 8], 1);   // LDS cursor holds global pos
        pairs[p] = ((uint)src[i] << 8) | (uint)(d & 255);
    }
}

// ---------------- level-2: per-bucket CSR build (exact, 256-node buckets) ----------------
__global__ __launch_bounds__(256) void build_csr(const uint* __restrict__ pairs,
                                                 const int* __restrict__ goff,
                                                 int* __restrict__ row_off,
                                                 float* __restrict__ disqrt,
                                                 int* __restrict__ col,
                                                 int E, int NC, int N) {
    __shared__ int h[256], cur[256];
    __shared__ int ws[4], wsoff[4];
    int b = blockIdx.x, t = threadIdx.x;
    int base = goff[(size_t)b * B1];
    int next = (b + 1 < NC) ? goff[(size_t)(b + 1) * B1] : E;
    h[t] = 0;
    __syncthreads();
    for (int i = base + t; i < next; i += 256)
        atomicAdd(&h[pairs[i] & 255u], 1);
    __syncthreads();
    int deg = h[t];
    int incl = deg;
#pragma unroll
    for (int o = 1; o < 64; o <<= 1) {
        int u = __shfl_up(incl, o, 64);
        if ((t & 63) >= o) incl += u;
    }
    if ((t & 63) == 63) ws[t >> 6] = incl;
    __syncthreads();
    if (t == 0) {
        int run = 0;
#pragma unroll
        for (int i = 0; i < 4; ++i) { wsoff[i] = run; run += ws[i]; }
    }
    __syncthreads();
    int excl = wsoff[t >> 6] + incl - deg;
    cur[t] = base + excl;
    int node = (b << 8) + t;
    if (node < N) {
        row_off[node] = base + excl;
        disqrt[node]  = rsqrtf((float)(deg + 1));  // +1 self-loop
    }
    __syncthreads();
    for (int i = base + t; i < next; i += 256) {
        uint p = pairs[i];
        int pos = atomicAdd(&cur[p & 255u], 1);   // LDS atomic, global pos
        col[pos] = (int)(p >> 8);                 // 16KB window, single XCD
    }
}

// ---------------- tiled GEMM (fp32 X, K=128): 128x64 tile, 8x4/thread ----------------
template <int K>
__global__ __launch_bounds__(256) void gemm_tile(const float* __restrict__ X,
                                                 const float* __restrict__ W,
                                                 const float* __restrict__ disqrt,
                                                 uint* __restrict__ Tsb, int n) {
    __shared__ float xs[32][132];  // [k][m], 128 rows +4 pad (16B-aligned rows)
    __shared__ float ws[32][64];   // [k][c]
    const int tid = threadIdx.x;
    const int ng  = tid & 15;      // cols 4*ng..+3
    const int mg  = tid >> 4;      // rows 8*mg..+7
    const int m0  = blockIdx.x * 128;
    const float4 z4 = make_float4(0.f, 0.f, 0.f, 0.f);
    int xr[4], xk[4];
#pragma unroll
    for (int i = 0; i < 4; ++i) { int f = tid + i * 256; xr[i] = f >> 3; xk[i] = f & 7; }
    const int wk0 = tid >> 4, wc0 = tid & 15;

    float4 gx[4], gw[2];
#pragma unroll
    for (int i = 0; i < 4; ++i) {
        int row = m0 + xr[i];
        gx[i] = (row < n) ? *(const float4*)(X + (size_t)row * K + 4 * xk[i]) : z4;
    }
    gw[0] = *(const float4*)(W + (size_t)wk0 * 64 + 4 * wc0);
    gw[1] = *(const float4*)(W + (size_t)(wk0 + 16) * 64 + 4 * wc0);

    float acc[8][4] = {};
    for (int kc = 0;;) {
#pragma unroll
        for (int i = 0; i < 4; ++i) {
            xs[4 * xk[i] + 0][xr[i]] = gx[i].x;
            xs[4 * xk[i] + 1][xr[i]] = gx[i].y;
            xs[4 * xk[i] + 2][xr[i]] = gx[i].z;
            xs[4 * xk[i] + 3][xr[i]] = gx[i].w;
        }
        *(float4*)&ws[wk0][4 * wc0]      = gw[0];
        *(float4*)&ws[wk0 + 16][4 * wc0] = gw[1];
        __syncthreads();
        kc += 32;
        const bool more = kc < K;
        if (more) {
#pragma unroll
            for (int i = 0; i < 4; ++i) {
                int row = m0 + xr[i];
                gx[i] = (row < n) ? *(const float4*)(X + (size_t)row * K + kc + 4 * xk[i]) : z4;
            }
            gw[0] = *(const float4*)(W + (size_t)(kc + wk0) * 64 + 4 * wc0);
            gw[1] = *(const float4*)(W + (size_t)(kc + wk0 + 16) * 64 + 4 * wc0);
        }
#pragma unroll 4
        for (int k = 0; k < 32; ++k) {
            float4 a0 = *(const float4*)&xs[k][8 * mg];
            float4 a1 = *(const float4*)&xs[k][8 * mg + 4];
            float4 b  = *(const float4*)&ws[k][4 * ng];
            const float* ap0 = (const float*)&a0;
            const float* ap1 = (const float*)&a1;
            const float* bp  = (const float*)&b;
#pragma unroll
            for (int mi = 0; mi < 4; ++mi)
#pragma unroll
                for (int ni = 0; ni < 4; ++ni) {
                    acc[mi][ni]     += ap0[mi] * bp[ni];
                    acc[mi + 4][ni] += ap1[mi] * bp[ni];
                }
        }
        if (!more) break;
        __syncthreads();
    }
#pragma unroll
    for (int mi = 0; mi < 8; ++mi) {
        int row = m0 + 8 * mg + mi;
        if (row < n) {
            float s = disqrt[row];
            uint2 pk;
            pk.x = pack_bf16x2(acc[mi][0] * s, acc[mi][1] * s);
            pk.y = pack_bf16x2(acc[mi][2] * s, acc[mi][3] * s);
            *(uint2*)(Tsb + (size_t)row * 32 + 2 * ng) = pk;
        }
    }
}

// ---------------- tiled GEMM (bf16 X, K=64): 128x64 tile, 8x4/thread ----------------
__global__ __launch_bounds__(256) void gemm_tile_b(const uint* __restrict__ Xb,
                                                   const float* __restrict__ W,
                                                   const float* __restrict__ disqrt,
                                                   uint* __restrict__ Tsb, int n) {
    const int K = 64;
    __shared__ float xs[32][132];
    __shared__ float ws[32][64];
    const int tid = threadIdx.x;
    const int ng  = tid & 15;
    const int mg  = tid >> 4;
    const int m0  = blockIdx.x * 128;
    const uint2 z2 = make_uint2(0u, 0u);
    int xr[4], xk[4];
#pragma unroll
    for (int i = 0; i < 4; ++i) { int f = tid + i * 256; xr[i] = f >> 3; xk[i] = f & 7; }
    const int wk0 = tid >> 4, wc0 = tid & 15;

    uint2 gx[4];
    float4 gw[2];
#pragma unroll
    for (int i = 0; i < 4; ++i) {
        int row = m0 + xr[i];
        gx[i] = (row < n) ? *(const uint2*)(Xb + (size_t)row * 32 + 2 * xk[i]) : z2;
    }
    gw[0] = *(const float4*)(W + (size_t)wk0 * 64 + 4 * wc0);
    gw[1] = *(const float4*)(W + (size_t)(wk0 + 16) * 64 + 4 * wc0);

    float acc[8][4] = {};
    for (int kc = 0;;) {
#pragma unroll
        for (int i = 0; i < 4; ++i) {
            xs[4 * xk[i] + 0][xr[i]] = bf_lo(gx[i].x);
            xs[4 * xk[i] + 1][xr[i]] = bf_hi(gx[i].x);
            xs[4 * xk[i] + 2][xr[i]] = bf_lo(gx[i].y);
            xs[4 * xk[i] + 3][xr[i]] = bf_hi(gx[i].y);
        }
        *(float4*)&ws[wk0][4 * wc0]      = gw[0];
        *(float4*)&ws[wk0 + 16][4 * wc0] = gw[1];
        __syncthreads();
        kc += 32;
        const bool more = kc < K;
        if (more) {
#pragma unroll
            for (int i = 0; i < 4; ++i) {
                int row = m0 + xr[i];
                gx[i] = (row < n) ? *(const uint2*)(Xb + (size_t)row * 32 + 16 + 2 * xk[i]) : z2;
            }
            gw[0] = *(const float4*)(W + (size_t)(kc + wk0) * 64 + 4 * wc0);
            gw[1] = *(const float4*)(W + (size_t)(kc + wk0 + 16) * 64 + 4 * wc0);
        }
#pragma unroll 4
        for (int k = 0; k < 32; ++k) {
            float4 a0 = *(const float4*)&xs[k][8 * mg];
            float4 a1 = *(const float4*)&xs[k][8 * mg + 4];
            float4 b  = *(const float4*)&ws[k][4 * ng];
            const float* ap0 = (const float*)&a0;
            const float* ap1 = (const float*)&a1;
            const float* bp  = (const float*)&b;
#pragma unroll
            for (int mi = 0; mi < 4; ++mi)
#pragma unroll
                for (int ni = 0; ni < 4; ++ni) {
                    acc[mi][ni]     += ap0[mi] * bp[ni];
                    acc[mi + 4][ni] += ap1[mi] * bp[ni];
                }
        }
        if (!more) break;
        __syncthreads();
    }
#pragma unroll
    for (int mi = 0; mi < 8; ++mi) {
        int row = m0 + 8 * mg + mi;
        if (row < n) {
            float s = disqrt[row];
            uint2 pk;
            pk.x = pack_bf16x2(acc[mi][0] * s, acc[mi][1] * s);
            pk.y = pack_bf16x2(acc[mi][2] * s, acc[mi][3] * s);
            *(uint2*)(Tsb + (size_t)row * 32 + 2 * ng) = pk;
        }
    }
}

// ---------------- aggregation: wave per node, eighth-wave per edge (FROZEN) ----------------
template <bool FUSE_FC>
__global__ __launch_bounds__(256) void agg_kernel(const uint* __restrict__ Tsb,
                                                  const int* __restrict__ row_off,
                                                  const int* __restrict__ col,
                                                  const float* __restrict__ disqrt,
                                                  const float* __restrict__ bias,
                                                  const float* __restrict__ wfc,
                                                  const float* __restrict__ bfc,
                                                  uint* __restrict__ outb,
                                                  float* __restrict__ outf, int n) {
    int node = blockIdx.x * 4 + (threadIdx.x >> 6);
    if (node >= n) return;
    int lane = threadIdx.x & 63;
    int o = lane >> 3;      // octant id: edge slot within group of 8
    int p = lane & 7;       // uint4 index (features 8p..8p+7)
    float acc[8] = {};
    if (o == 0) {   // self-loop, octant 0 only
        uint4 g = *(const uint4*)(Tsb + (size_t)node * 32 + 4 * p);
        acc[0] = bf_lo(g.x); acc[1] = bf_hi(g.x);
        acc[2] = bf_lo(g.y); acc[3] = bf_hi(g.y);
        acc[4] = bf_lo(g.z); acc[5] = bf_hi(g.z);
        acc[6] = bf_lo(g.w); acc[7] = bf_hi(g.w);
    }
    int beg = __builtin_amdgcn_readfirstlane(row_off[node]);
    int end = __builtin_amdgcn_readfirstlane(row_off[node + 1]);
    for (int batch = beg; batch < end; batch += 64) {
        int bn = min(64, end - batch);
        int cv = 0;
        if (batch + lane < end) cv = col[batch + lane];  // ONE coalesced load
        int j = 0;
        for (; j + 16 <= bn; j += 16) {
            int s0 = __shfl(cv, j + o, 64);
            int s1 = __shfl(cv, j + 8 + o, 64);
            uint4 g0 = *(const uint4*)(Tsb + (size_t)s0 * 32 + 4 * p);
            uint4 g1 = *(const uint4*)(Tsb + (size_t)s1 * 32 + 4 * p);
            acc[0] += bf_lo(g0.x); acc[1] += bf_hi(g0.x);
            acc[2] += bf_lo(g0.y); acc[3] += bf_hi(g0.y);
            acc[4] += bf_lo(g0.z); acc[5] += bf_hi(g0.z);
            acc[6] += bf_lo(g0.w); acc[7] += bf_hi(g0.w);
            acc[0] += bf_lo(g1.x); acc[1] += bf_hi(g1.x);
            acc[2] += bf_lo(g1.y); acc[3] += bf_hi(g1.y);
            acc[4] += bf_lo(g1.z); acc[5] += bf_hi(g1.z);
            acc[6] += bf_lo(g1.w); acc[7] += bf_hi(g1.w);
        }
        for (; j < bn; j += 8) {
            int idx = j + o;
            int s = __shfl(cv, idx & 63, 64);
            uint4 g = *(const uint4*)(Tsb + (size_t)s * 32 + 4 * p);
            if (idx < bn) {
                acc[0] += bf_lo(g.x); acc[1] += bf_hi(g.x);
                acc[2] += bf_lo(g.y); acc[3] += bf_hi(g.y);
                acc[4] += bf_lo(g.z); acc[5] += bf_hi(g.z);
                acc[6] += bf_lo(g.w); acc[7] += bf_hi(g.w);
            }
        }
    }
#pragma unroll
    for (int k = 0; k < 8; ++k) {
        acc[k] += __shfl_xor(acc[k], 8, 64);
        acc[k] += __shfl_xor(acc[k], 16, 64);
        acc[k] += __shfl_xor(acc[k], 32, 64);
    }
    float dq = disqrt[node];
    float4 bv0 = *(const float4*)(bias + 8 * p);
    float4 bv1 = *(const float4*)(bias + 8 * p + 4);
    float r[8];
    r[0] = fmaxf(acc[0] * dq + bv0.x, 0.f);
    r[1] = fmaxf(acc[1] * dq + bv0.y, 0.f);
    r[2] = fmaxf(acc[2] * dq + bv0.z, 0.f);
    r[3] = fmaxf(acc[3] * dq + bv0.w, 0.f);
    r[4] = fmaxf(acc[4] * dq + bv1.x, 0.f);
    r[5] = fmaxf(acc[5] * dq + bv1.y, 0.f);
    r[6] = fmaxf(acc[6] * dq + bv1.z, 0.f);
    r[7] = fmaxf(acc[7] * dq + bv1.w, 0.f);
    if (!FUSE_FC) {
        if (o == 0) {   // pack to bf16 for gemm_tile_b
            uint4 pk;
            pk.x = pack_bf16x2(r[0], r[1]);
            pk.y = pack_bf16x2(r[2], r[3]);
            pk.z = pack_bf16x2(r[4], r[5]);
            pk.w = pack_bf16x2(r[6], r[7]);
            *(uint4*)(outb + (size_t)node * 32 + 4 * p) = pk;
        }
    } else {
        float4 wv0 = *(const float4*)(wfc + 8 * p);
        float4 wv1 = *(const float4*)(wfc + 8 * p + 4);
        float v = r[0] * wv0.x + r[1] * wv0.y + r[2] * wv0.z + r[3] * wv0.w +
                  r[4] * wv1.x + r[5] * wv1.y + r[6] * wv1.z + r[7] * wv1.w;
        v += __shfl_down(v, 4, 64);
        v += __shfl_down(v, 2, 64);
        v += __shfl_down(v, 1, 64);
        if (lane == 0) outf[node] = v + bfc[0];
    }
}

extern "C" void kernel_launch(void* const* d_in, const int* in_sizes, int n_in,
                              void* d_out, int out_size, void* d_ws, size_t ws_size,
                              hipStream_t stream) {
    const float* x   = (const float*)d_in[0];
    const int*   ei  = (const int*)d_in[1];
    const float* W1  = (const float*)d_in[2];
    const float* b1  = (const float*)d_in[3];
    const float* W2  = (const float*)d_in[4];
    const float* b2  = (const float*)d_in[5];
    const float* Wfc = (const float*)d_in[6];
    const float* bfc = (const float*)d_in[7];
    float* out = (float*)d_out;

    const int N = in_sizes[0] / IN_DIM;
    const int E = in_sizes[1] / 2;
    const int* src = ei;
    const int* dst = ei + E;
    const int NC    = (N + 255) >> 8;        // 256-node buckets
    const int chunk = (E + B1 - 1) / B1;     // edges per level-1 block
    const int M     = NC * B1;               // ghist size
    const int NBs   = (M + 255) / 256;       // scan blocks (<= 512)

    // ---- workspace carve-up (256B aligned) ----
    char* w = (char*)d_ws;
    auto alloc = [&](size_t bytes) {
        void* p = (void*)w;
        w += (bytes + 255) & ~(size_t)255;
        return p;
    };
    int*   row_off = (int*)alloc((size_t)(N + 1) * 4);
    float* disqrt  = (float*)alloc((size_t)N * 4);
    int*   goff    = (int*)alloc((size_t)NC * B1 * 4);
    int*   bsum    = (int*)alloc(512 * 4);
    int*   boff    = (int*)alloc(512 * 4);
    int*   col     = (int*)alloc((size_t)E * 4);
    // scratch region reused: packed pairs (E*4) first, then Ts bf16 (N*128B)
    size_t scrA = (size_t)E * 4, scrB = (size_t)N * HID * 2;
    void*  scr  = alloc(scrA > scrB ? scrA : scrB);
    uint*  h1b  = (uint*)alloc((size_t)N * HID * 2);   // h1 in packed bf16
    uint*  pairs = (uint*)scr;
    uint*  Tsb   = (uint*)scr;

    // ---- build CSR (exact two-level counting sort, packed pairs) ----
    hist1<<<B1, 512, 0, stream>>>(dst, goff, E, NC, chunk);
    scan_p1<<<NBs, 256, 0, stream>>>(goff, bsum, M);
    scan_p2<<<1, 512, 0, stream>>>(bsum, boff, row_off, NBs, N);
    scan_p3<<<NBs, 256, 0, stream>>>(goff, boff, M);
    scatter1<<<B1, 512, 0, stream>>>(src, dst, goff, pairs, E, NC, chunk);
    build_csr<<<NC, 256, 0, stream>>>(pairs, goff, row_off, disqrt, col, E, NC, N);

    // ---- layer 1 ----
    gemm_tile<IN_DIM><<<(N + 127) / 128, 256, 0, stream>>>(x, W1, disqrt, Tsb, N);
    agg_kernel<false><<<(N + 3) / 4, 256, 0, stream>>>(Tsb, row_off, col, disqrt,
                                                       b1, nullptr, nullptr,
                                                       h1b, nullptr, N);

    // ---- layer 2 + fused fc ----
    gemm_tile_b<<<(N + 127) / 128, 256, 0, stream>>>(h1b, W2, disqrt, Tsb, N);
    agg_kernel<true><<<(N + 3) / 4, 256, 0, stream>>>(Tsb, row_off, col, disqrt,
                                                      b2, Wfc, bfc,
                                                      nullptr, out, N);
}